// Round 16
// baseline (1781.068 us; speedup 1.0000x reference)
//
#include <hip/hip_runtime.h>
#include <math.h>

#define BB 128
#define TT 2048
#define II 128
#define UU 256
#define OO 128

typedef __attribute__((ext_vector_type(8))) short bf16x8;
typedef __attribute__((ext_vector_type(4))) float f32x4;

#define MFMA16(a, b, cacc) __builtin_amdgcn_mfma_f32_16x16x32_bf16(a, b, cacc, 0, 0, 0)

// LDS-only barrier (rule 18): orders LDS ops without draining vmcnt.
__device__ __forceinline__ void bar_lds() {
    __builtin_amdgcn_sched_barrier(0);
    asm volatile("s_waitcnt lgkmcnt(0)" ::: "memory");
    __builtin_amdgcn_s_barrier();
    __builtin_amdgcn_sched_barrier(0);
}

// float -> bf16 round-to-nearest-even
__device__ __forceinline__ short f2bf(float f) {
    unsigned u = __float_as_uint(f);
    unsigned r = (u + 0x7FFFu + ((u >> 16) & 1u)) >> 16;
    return (short)r;
}

__device__ __forceinline__ bf16x8 loadf8(const float* p) {
    float4 va = *reinterpret_cast<const float4*>(p);
    float4 vb = *reinterpret_cast<const float4*>(p + 4);
    bf16x8 v;
    v[0] = f2bf(va.x); v[1] = f2bf(va.y); v[2] = f2bf(va.z); v[3] = f2bf(va.w);
    v[4] = f2bf(vb.x); v[5] = f2bf(vb.y); v[6] = f2bf(vb.z); v[7] = f2bf(vb.w);
    return v;
}

// ---------------- Kernel 1: input projection as MFMA GEMM -----------------
// (unchanged, validated r11 — near HBM floor)
__global__ __launch_bounds__(256, 2) void k_inproj(
    const float* __restrict__ x, const float* __restrict__ Wih,
    const float* __restrict__ bih, const float* __restrict__ bhh,
    float* __restrict__ xp)
{
    __shared__ __align__(16) short xs[64 * 128];   // 16 KB bf16, swizzled
    const int tid = threadIdx.x;
    const int w = tid >> 6;
    const int lane = tid & 63;
    const int g = lane >> 4;
    const int c = lane & 15;
    bf16x8 wb[4][4];
    float bias[4];
    #pragma unroll
    for (int nt = 0; nt < 4; ++nt) {
        const int u = w * 64 + nt * 16 + c;
        #pragma unroll
        for (int kt = 0; kt < 4; ++kt)
            wb[nt][kt] = loadf8(&Wih[(size_t)u * II + kt * 32 + g * 8]);
        bias[nt] = bih[u] + bhh[u];
    }
    const int srow = tid >> 2, sq = tid & 3;       // staging: 4 thr/row
    const int ntiles = (BB * TT) / 64;             // 4096
    for (int tile = blockIdx.x; tile < ntiles; tile += gridDim.x) {
        const size_t rowbase = (size_t)tile * 64;
        #pragma unroll
        for (int t2 = 0; t2 < 4; ++t2) {
            int n = sq * 4 + t2;                   // 16B chunk index 0..15
            const float* src = &x[(rowbase + srow) * II + n * 8];
            bf16x8 v = loadf8(src);
            int off = srow * 128 + ((n * 8) ^ ((srow & 7) << 3));
            *reinterpret_cast<bf16x8*>(&xs[off]) = v;
        }
        __syncthreads();
        #pragma unroll
        for (int mt = 0; mt < 4; ++mt) {
            const int row = mt * 16 + c;
            bf16x8 af[4];
            #pragma unroll
            for (int kt = 0; kt < 4; ++kt)
                af[kt] = *reinterpret_cast<const bf16x8*>(
                    &xs[row * 128 + ((kt * 32 + g * 8) ^ ((c & 7) << 3))]);
            f32x4 acc[4];
            #pragma unroll
            for (int nt = 0; nt < 4; ++nt) acc[nt] = (f32x4){0.f,0.f,0.f,0.f};
            #pragma unroll
            for (int kt = 0; kt < 4; ++kt)
                #pragma unroll
                for (int nt = 0; nt < 4; ++nt)
                    acc[nt] = MFMA16(af[kt], wb[nt][kt], acc[nt]);
            #pragma unroll
            for (int nt = 0; nt < 4; ++nt)
                #pragma unroll
                for (int r = 0; r < 4; ++r)
                    xp[(rowbase + mt * 16 + g * 4 + r) * UU + w * 64 + nt * 16 + c]
                        = acc[nt][r] + bias[nt];
        }
        __syncthreads();
    }
}

// ---------------- Kernel 2: DUAL serial recurrence per block --------------
// 64 blocks x 512 thr (8 waves, 2/SIMD). Block bid runs TWO independent
// batches {bid, bid+64}, interleaved in the same inter-barrier body so
// sequence B's issue fills sequence A's latency bubbles (LDS-read ~120cy,
// MFMA latency, tanh chain). W_hh B-fragments (64 VGPR) are SHARED by both
// sequences — second sequence costs only ~70 VGPR (acc+A+xp) -> ~190 total.
// Per sequence: r8-exact math (16 MFMA, 8 acc slots, replicated-A GEMV,
// lane owns u = w*32+(g&1)*16+c). ONE barrier per step-pair.
__global__ __launch_bounds__(512, 2) void k_rnn2(
    const float* __restrict__ Whh, float* __restrict__ xph)
{
    __shared__ __align__(16) short hbuf[2][2 * 256];  // [seq][dbuf x 256] bf16
    const int tid = threadIdx.x;
    const int w = tid >> 6;
    const int lane = tid & 63;
    const int g = lane >> 4;
    const int c = lane & 15;
    bf16x8 bq[2][8];                               // shared by both sequences
    #pragma unroll
    for (int q2 = 0; q2 < 2; ++q2) {
        const int ub = w * 32 + q2 * 16 + c;
        #pragma unroll
        for (int kt = 0; kt < 8; ++kt)
            bq[q2][kt] = loadf8(&Whh[(size_t)ub * UU + kt * 32 + g * 8]);
    }
    const int q = g & 1;
    const int uxp = w * 32 + q * 16 + c;
    const bool gl = (g < 2);
    const bool kill = (uxp == 3) || (uxp == 7);

    if (tid < 256) {
        reinterpret_cast<int*>(hbuf[0])[tid] = 0;
        reinterpret_cast<int*>(hbuf[1])[tid] = 0;
    }
    __syncthreads();

    float* rowpA = xph + (size_t)blockIdx.x * (size_t)TT * UU;
    float* rowpB = xph + (size_t)(blockIdx.x + 64) * (size_t)TT * UU;
    float xpvA = rowpA[uxp],      xpvB = rowpB[uxp];
    float xpnA = rowpA[UU + uxp], xpnB = rowpB[UU + uxp];

    auto step = [&](int t, int p) {
        int tn = t + 2; tn = (tn < TT) ? tn : (TT - 1);
        float xpn2A = rowpA[(size_t)tn * UU + uxp];
        float xpn2B = rowpB[(size_t)tn * UU + uxp];
        const bf16x8* hbA = reinterpret_cast<const bf16x8*>(hbuf[0] + p * 256);
        const bf16x8* hbB = reinterpret_cast<const bf16x8*>(hbuf[1] + p * 256);
        f32x4 accA0[4], accA1[4], accB0[4], accB1[4];
        #pragma unroll
        for (int i = 0; i < 4; ++i) {
            accA0[i] = (f32x4){0.f, 0.f, 0.f, 0.f};
            accA1[i] = (f32x4){0.f, 0.f, 0.f, 0.f};
            accB0[i] = (f32x4){0.f, 0.f, 0.f, 0.f};
            accB1[i] = (f32x4){0.f, 0.f, 0.f, 0.f};
        }
        #pragma unroll
        for (int kt = 0; kt < 8; ++kt) {
            bf16x8 aA = hbA[kt * 4 + g];
            bf16x8 aB = hbB[kt * 4 + g];
            accA0[kt & 3] = MFMA16(aA, bq[0][kt], accA0[kt & 3]);
            accA1[kt & 3] = MFMA16(aA, bq[1][kt], accA1[kt & 3]);
            accB0[kt & 3] = MFMA16(aB, bq[0][kt], accB0[kt & 3]);
            accB1[kt & 3] = MFMA16(aB, bq[1][kt], accB1[kt & 3]);
        }
        float dA0 = (accA0[0][0] + accA0[1][0]) + (accA0[2][0] + accA0[3][0]);
        float dA1 = (accA1[0][0] + accA1[1][0]) + (accA1[2][0] + accA1[3][0]);
        float dB0 = (accB0[0][0] + accB0[1][0]) + (accB0[2][0] + accB0[3][0]);
        float dB1 = (accB1[0][0] + accB1[1][0]) + (accB1[2][0] + accB1[3][0]);
        float sA = (q ? dA1 : dA0) + xpvA;
        float sB = (q ? dB1 : dB0) + xpvB;
        float hrA = 1.0f - 2.0f / (__expf(2.0f * sA) + 1.0f);
        float hrB = 1.0f - 2.0f / (__expf(2.0f * sB) + 1.0f);
        if (gl) {
            rowpA[(size_t)t * UU + uxp] = hrA;               // h_raw (fp32)
            rowpB[(size_t)t * UU + uxp] = hrB;
        } else {
            hbuf[0][(p ^ 1) * 256 + uxp] = kill ? (short)0 : f2bf(hrA);
            hbuf[1][(p ^ 1) * 256 + uxp] = kill ? (short)0 : f2bf(hrB);
        }
        bar_lds();
        xpvA = xpnA; xpnA = xpn2A;
        xpvB = xpnB; xpnB = xpn2B;
    };
    for (int t = 0; t < TT; t += 2) { step(t, 0); step(t + 1, 1); }
}

// ---------------- Kernel 3: readout as MFMA GEMM + mask fix-up ------------
// (unchanged, validated r11 — near HBM floor)
__global__ __launch_bounds__(256, 2) void k_readout(
    const float* __restrict__ Wfc, const float* __restrict__ bfc,
    float* __restrict__ hraw, float* __restrict__ outR)
{
    __shared__ __align__(16) short hs[64 * 256];   // 32 KB bf16, swizzled
    const int tid = threadIdx.x;
    const int w = tid >> 6;
    const int lane = tid & 63;
    const int g = lane >> 4;
    const int c = lane & 15;
    bf16x8 wb[2][8];
    float bias[2];
    #pragma unroll
    for (int nt = 0; nt < 2; ++nt) {
        const int o = w * 32 + nt * 16 + c;
        #pragma unroll
        for (int kt = 0; kt < 8; ++kt)
            wb[nt][kt] = loadf8(&Wfc[(size_t)o * UU + kt * 32 + g * 8]);
        bias[nt] = bfc[o];
    }
    const int srow = tid >> 2, sq = tid & 3;       // staging: 4 thr/row
    const int ntiles = (BB * TT) / 64;             // 4096
    for (int tile = blockIdx.x; tile < ntiles; tile += gridDim.x) {
        const size_t rowbase = (size_t)tile * 64;
        #pragma unroll
        for (int t2 = 0; t2 < 8; ++t2) {
            int n = sq * 8 + t2;                   // 16B chunk 0..31
            const float* src = &hraw[(rowbase + srow) * UU + n * 8];
            bf16x8 v = loadf8(src);
            int off = srow * 256 + ((n * 8) ^ ((srow & 7) << 3));
            *reinterpret_cast<bf16x8*>(&hs[off]) = v;
        }
        __syncthreads();
        // raw values staged: zero killed units in the global hs output
        if (tid < 128) {
            int r = tid >> 1, col = (tid & 1) ? 7 : 3;
            hraw[(rowbase + r) * UU + col] = 0.f;
        }
        #pragma unroll
        for (int mt = 0; mt < 4; ++mt) {
            const int row = mt * 16 + c;
            f32x4 acc[2];
            acc[0] = (f32x4){0.f,0.f,0.f,0.f};
            acc[1] = (f32x4){0.f,0.f,0.f,0.f};
            #pragma unroll
            for (int kt = 0; kt < 8; ++kt) {
                bf16x8 af = *reinterpret_cast<const bf16x8*>(
                    &hs[row * 256 + ((kt * 32 + g * 8) ^ ((c & 7) << 3))]);
                acc[0] = MFMA16(af, wb[0][kt], acc[0]);
                acc[1] = MFMA16(af, wb[1][kt], acc[1]);
            }
            #pragma unroll
            for (int nt = 0; nt < 2; ++nt)
                #pragma unroll
                for (int r = 0; r < 4; ++r)
                    outR[(rowbase + mt * 16 + g * 4 + r) * OO + w * 32 + nt * 16 + c]
                        = acc[nt][r] + bias[nt];
        }
        __syncthreads();
    }
}

extern "C" void kernel_launch(void* const* d_in, const int* in_sizes, int n_in,
                              void* d_out, int out_size, void* d_ws, size_t ws_size,
                              hipStream_t stream) {
    const float* x   = (const float*)d_in[0];
    const float* Wih = (const float*)d_in[1];
    const float* Whh = (const float*)d_in[2];
    const float* bih = (const float*)d_in[3];
    const float* bhh = (const float*)d_in[4];
    const float* Wfc = (const float*)d_in[5];
    const float* bfc = (const float*)d_in[6];
    float* outR = (float*)d_out;                       // readouts [B,T,O]
    float* outH = outR + (size_t)BB * TT * OO;         // hs       [B,T,U]

    k_inproj<<<512, 256, 0, stream>>>(x, Wih, bih, bhh, outH);
    k_rnn2<<<64, 512, 0, stream>>>(Whh, outH);
    k_readout<<<512, 256, 0, stream>>>(Wfc, bfc, outH, outR);
}

// Round 17
// 1251.006 us; speedup vs baseline: 1.4237x; 1.4237x over previous
//
#include <hip/hip_runtime.h>
#include <math.h>

#define BB 128
#define TT 2048
#define II 128
#define UU 256
#define OO 128

typedef __attribute__((ext_vector_type(8))) short bf16x8;
typedef __attribute__((ext_vector_type(4))) float f32x4;

#define MFMA16(a, b, cacc) __builtin_amdgcn_mfma_f32_16x16x32_bf16(a, b, cacc, 0, 0, 0)

// LDS-only barrier (rule 18): orders LDS ops without draining vmcnt.
__device__ __forceinline__ void bar_lds() {
    __builtin_amdgcn_sched_barrier(0);
    asm volatile("s_waitcnt lgkmcnt(0)" ::: "memory");
    __builtin_amdgcn_s_barrier();
    __builtin_amdgcn_sched_barrier(0);
}

// float -> bf16 round-to-nearest-even
__device__ __forceinline__ short f2bf(float f) {
    unsigned u = __float_as_uint(f);
    unsigned r = (u + 0x7FFFu + ((u >> 16) & 1u)) >> 16;
    return (short)r;
}

__device__ __forceinline__ bf16x8 loadf8(const float* p) {
    float4 va = *reinterpret_cast<const float4*>(p);
    float4 vb = *reinterpret_cast<const float4*>(p + 4);
    bf16x8 v;
    v[0] = f2bf(va.x); v[1] = f2bf(va.y); v[2] = f2bf(va.z); v[3] = f2bf(va.w);
    v[4] = f2bf(vb.x); v[5] = f2bf(vb.y); v[6] = f2bf(vb.z); v[7] = f2bf(vb.w);
    return v;
}

// ---------------- Kernel 1: input projection as MFMA GEMM -----------------
// xp[row,u] = x[row,:].Wih[u,:] + bih[u] + bhh[u].  M=262144, N=256, K=128.
// 256 thr = 4 waves; tile = 64 rows. Wave w owns n-range w*64 (4 n-tiles).
// x tile staged bf16 in LDS with XOR swizzle; ~HBM floor (validated r11).
__global__ __launch_bounds__(256, 2) void k_inproj(
    const float* __restrict__ x, const float* __restrict__ Wih,
    const float* __restrict__ bih, const float* __restrict__ bhh,
    float* __restrict__ xp)
{
    __shared__ __align__(16) short xs[64 * 128];   // 16 KB bf16, swizzled
    const int tid = threadIdx.x;
    const int w = tid >> 6;
    const int lane = tid & 63;
    const int g = lane >> 4;
    const int c = lane & 15;
    bf16x8 wb[4][4];
    float bias[4];
    #pragma unroll
    for (int nt = 0; nt < 4; ++nt) {
        const int u = w * 64 + nt * 16 + c;
        #pragma unroll
        for (int kt = 0; kt < 4; ++kt)
            wb[nt][kt] = loadf8(&Wih[(size_t)u * II + kt * 32 + g * 8]);
        bias[nt] = bih[u] + bhh[u];
    }
    const int srow = tid >> 2, sq = tid & 3;       // staging: 4 thr/row
    const int ntiles = (BB * TT) / 64;             // 4096
    for (int tile = blockIdx.x; tile < ntiles; tile += gridDim.x) {
        const size_t rowbase = (size_t)tile * 64;
        #pragma unroll
        for (int t2 = 0; t2 < 4; ++t2) {
            int n = sq * 4 + t2;                   // 16B chunk index 0..15
            const float* src = &x[(rowbase + srow) * II + n * 8];
            bf16x8 v = loadf8(src);
            int off = srow * 128 + ((n * 8) ^ ((srow & 7) << 3));
            *reinterpret_cast<bf16x8*>(&xs[off]) = v;
        }
        __syncthreads();
        #pragma unroll
        for (int mt = 0; mt < 4; ++mt) {
            const int row = mt * 16 + c;
            bf16x8 af[4];
            #pragma unroll
            for (int kt = 0; kt < 4; ++kt)
                af[kt] = *reinterpret_cast<const bf16x8*>(
                    &xs[row * 128 + ((kt * 32 + g * 8) ^ ((c & 7) << 3))]);
            f32x4 acc[4];
            #pragma unroll
            for (int nt = 0; nt < 4; ++nt) acc[nt] = (f32x4){0.f,0.f,0.f,0.f};
            #pragma unroll
            for (int kt = 0; kt < 4; ++kt)
                #pragma unroll
                for (int nt = 0; nt < 4; ++nt)
                    acc[nt] = MFMA16(af[kt], wb[nt][kt], acc[nt]);
            #pragma unroll
            for (int nt = 0; nt < 4; ++nt)
                #pragma unroll
                for (int r = 0; r < 4; ++r)
                    xp[(rowbase + mt * 16 + g * 4 + r) * UU + w * 64 + nt * 16 + c]
                        = acc[nt][r] + bias[nt];
        }
        __syncthreads();
    }
}

// ---------------- Kernel 2: serial recurrence (r8 body, 546 ns/step) ------
// 1 block/batch, 512 thr = 8 waves (2/SIMD). h (bf16, replicated A) x
// W_hh bf16 B fragments; 16 MFMA into 8 independent acc slots (depth 2).
// Lane owns u = w*32+(g&1)*16+(lane&15) via C/D col=lane&15. g<2 lanes
// write h_raw (fp32) to global; g>=2 write masked bf16 LDS carry.
// Step floor ~1310 cyc: per-CU matrix pipe ~620 (invariant across all
// decompositions: replication-waste x block-count cancels) + cross-wave
// LDS h-exchange round-trip + tanh chain + barrier skew. Nine structural
// variants (r4-r16) bracket this as the floor for the serial chain.
__global__ __launch_bounds__(512, 2) void k_rnn(
    const float* __restrict__ Whh, float* __restrict__ xph)
{
    __shared__ __align__(16) short hbuf[2 * 256];  // 2 x 256 bf16 = 1 KB
    const int tid = threadIdx.x;
    const int w = tid >> 6;
    const int lane = tid & 63;
    const int g = lane >> 4;
    const int c = lane & 15;
    bf16x8 bq[2][8];
    #pragma unroll
    for (int q2 = 0; q2 < 2; ++q2) {
        const int ub = w * 32 + q2 * 16 + c;
        #pragma unroll
        for (int kt = 0; kt < 8; ++kt)
            bq[q2][kt] = loadf8(&Whh[(size_t)ub * UU + kt * 32 + g * 8]);
    }
    const int q = g & 1;
    const int uxp = w * 32 + q * 16 + c;
    const bool gl = (g < 2);
    const bool kill = (uxp == 3) || (uxp == 7);

    if (tid < 256) reinterpret_cast<int*>(hbuf)[tid] = 0;
    __syncthreads();

    float* rowp = xph + (size_t)blockIdx.x * (size_t)TT * UU;
    float xpv = rowp[uxp];
    float xpn = rowp[UU + uxp];

    auto step = [&](int t, int p) {
        int tn = t + 2; tn = (tn < TT) ? tn : (TT - 1);
        float xpn2 = rowp[(size_t)tn * UU + uxp];
        const bf16x8* hb = reinterpret_cast<const bf16x8*>(hbuf + p * 256);
        f32x4 acc0[4], acc1[4];
        #pragma unroll
        for (int i = 0; i < 4; ++i) {
            acc0[i] = (f32x4){0.f, 0.f, 0.f, 0.f};
            acc1[i] = (f32x4){0.f, 0.f, 0.f, 0.f};
        }
        #pragma unroll
        for (int kt = 0; kt < 8; ++kt) {
            bf16x8 a = hb[kt * 4 + g];
            acc0[kt & 3] = MFMA16(a, bq[0][kt], acc0[kt & 3]);
            acc1[kt & 3] = MFMA16(a, bq[1][kt], acc1[kt & 3]);
        }
        float d0 = (acc0[0][0] + acc0[1][0]) + (acc0[2][0] + acc0[3][0]);
        float d1 = (acc1[0][0] + acc1[1][0]) + (acc1[2][0] + acc1[3][0]);
        float Dres = q ? d1 : d0;
        float s = Dres + xpv;
        float hr = 1.0f - 2.0f / (__expf(2.0f * s) + 1.0f);
        if (gl) {
            rowp[(size_t)t * UU + uxp] = hr;                    // h_raw (fp32)
        } else {
            hbuf[(p ^ 1) * 256 + uxp] = kill ? (short)0 : f2bf(hr);
        }
        bar_lds();
        xpv = xpn; xpn = xpn2;
    };
    for (int t = 0; t < TT; t += 2) { step(t, 0); step(t + 1, 1); }
}

// ---------------- Kernel 3: readout as MFMA GEMM + mask fix-up ------------
// readout[row,o] = h_raw[row,:].Wfc[o,:] + bfc[o].  M=262144, N=128, K=256.
// h_raw staged bf16 swizzled; cols {3,7} of global h_raw zeroed in place so
// the hs output becomes the masked hidden state. ~HBM floor (validated r11).
__global__ __launch_bounds__(256, 2) void k_readout(
    const float* __restrict__ Wfc, const float* __restrict__ bfc,
    float* __restrict__ hraw, float* __restrict__ outR)
{
    __shared__ __align__(16) short hs[64 * 256];   // 32 KB bf16, swizzled
    const int tid = threadIdx.x;
    const int w = tid >> 6;
    const int lane = tid & 63;
    const int g = lane >> 4;
    const int c = lane & 15;
    bf16x8 wb[2][8];
    float bias[2];
    #pragma unroll
    for (int nt = 0; nt < 2; ++nt) {
        const int o = w * 32 + nt * 16 + c;
        #pragma unroll
        for (int kt = 0; kt < 8; ++kt)
            wb[nt][kt] = loadf8(&Wfc[(size_t)o * UU + kt * 32 + g * 8]);
        bias[nt] = bfc[o];
    }
    const int srow = tid >> 2, sq = tid & 3;       // staging: 4 thr/row
    const int ntiles = (BB * TT) / 64;             // 4096
    for (int tile = blockIdx.x; tile < ntiles; tile += gridDim.x) {
        const size_t rowbase = (size_t)tile * 64;
        #pragma unroll
        for (int t2 = 0; t2 < 8; ++t2) {
            int n = sq * 8 + t2;                   // 16B chunk 0..31
            const float* src = &hraw[(rowbase + srow) * UU + n * 8];
            bf16x8 v = loadf8(src);
            int off = srow * 256 + ((n * 8) ^ ((srow & 7) << 3));
            *reinterpret_cast<bf16x8*>(&hs[off]) = v;
        }
        __syncthreads();
        // raw values staged: zero killed units in the global hs output
        if (tid < 128) {
            int r = tid >> 1, col = (tid & 1) ? 7 : 3;
            hraw[(rowbase + r) * UU + col] = 0.f;
        }
        #pragma unroll
        for (int mt = 0; mt < 4; ++mt) {
            const int row = mt * 16 + c;
            f32x4 acc[2];
            acc[0] = (f32x4){0.f,0.f,0.f,0.f};
            acc[1] = (f32x4){0.f,0.f,0.f,0.f};
            #pragma unroll
            for (int kt = 0; kt < 8; ++kt) {
                bf16x8 af = *reinterpret_cast<const bf16x8*>(
                    &hs[row * 256 + ((kt * 32 + g * 8) ^ ((c & 7) << 3))]);
                acc[0] = MFMA16(af, wb[0][kt], acc[0]);
                acc[1] = MFMA16(af, wb[1][kt], acc[1]);
            }
            #pragma unroll
            for (int nt = 0; nt < 2; ++nt)
                #pragma unroll
                for (int r = 0; r < 4; ++r)
                    outR[(rowbase + mt * 16 + g * 4 + r) * OO + w * 32 + nt * 16 + c]
                        = acc[nt][r] + bias[nt];
        }
        __syncthreads();
    }
}

extern "C" void kernel_launch(void* const* d_in, const int* in_sizes, int n_in,
                              void* d_out, int out_size, void* d_ws, size_t ws_size,
                              hipStream_t stream) {
    const float* x   = (const float*)d_in[0];
    const float* Wih = (const float*)d_in[1];
    const float* Whh = (const float*)d_in[2];
    const float* bih = (const float*)d_in[3];
    const float* bhh = (const float*)d_in[4];
    const float* Wfc = (const float*)d_in[5];
    const float* bfc = (const float*)d_in[6];
    float* outR = (float*)d_out;                       // readouts [B,T,O]
    float* outH = outR + (size_t)BB * TT * OO;         // hs       [B,T,U]

    k_inproj<<<512, 256, 0, stream>>>(x, Wih, bih, bhh, outH);
    k_rnn<<<128, 512, 0, stream>>>(Whh, outH);
    k_readout<<<512, 256, 0, stream>>>(Wfc, bfc, outH, outR);
}